// Round 1
// baseline (37.530 us; speedup 1.0000x reference)
//
#include <hip/hip_runtime.h>
#include <math.h>

#define SR_I 16000
#define FRAMES 500
#define UP 64
#define AUDIO (FRAMES * UP)
#define POLY 8
#define HARM 64
#define NYQ 8000.0f

// -------------------------------------------------------------------------
// Kernel 1: per (b,p) row, compute exclusive f64 prefix of per-frame sums of
// upsample(f0)/SR.  Frame sum closed form (scale=64, align_corners=False):
//   interior t:  8*x[t-1] + 48*x[t] + 8*x[t+1]
//   t = 0     : 56*x[0]   + 8*x[1]
//   t = 499   :  8*x[498] + 56*x[499]
// Output P[bp][t] = sum of frame sums for frames < t (in revolutions: /SR).
// -------------------------------------------------------------------------
__global__ __launch_bounds__(64) void k_prefix(const float* __restrict__ f0,
                                               double* __restrict__ P) {
    const int bp = blockIdx.x;      // 0..15  (b*8 + p)
    const int lane = threadIdx.x;   // 0..63
    const float* x = f0 + bp * FRAMES;
    double* Pp = P + bp * FRAMES;

    double carry = 0.0;
    for (int ch = 0; ch < 8; ++ch) {
        int t = ch * 64 + lane;
        double F = 0.0;
        if (t < FRAMES) {
            double xm = (double)x[t > 0 ? t - 1 : 0];
            double xc = (double)x[t];
            double xp = (double)x[t < FRAMES - 1 ? t + 1 : FRAMES - 1];
            double wa = 8.0, wb = 48.0, wc = 8.0;
            if (t == 0)          { wa = 0.0; wb = 56.0; wc = 8.0; }
            if (t == FRAMES - 1) { wa = 8.0; wb = 56.0; wc = 0.0; }
            F = (wa * xm + wb * xc + wc * xp) * (1.0 / (double)SR_I);
        }
        // inclusive wave scan (f64)
        double s = F;
        #pragma unroll
        for (int off = 1; off < 64; off <<= 1) {
            double o = __shfl_up(s, off, 64);
            if (lane >= off) s += o;
        }
        if (t < FRAMES) Pp[t] = carry + (s - F);   // exclusive prefix
        carry += __shfl(s, 63, 64);                 // add chunk total
    }
}

// -------------------------------------------------------------------------
// Kernel 2: one block per (b, frame t); 4 waves; wave w handles poly voices
// {2w, 2w+1}.  Lane k owns output sample j = t*64 + k.
// -------------------------------------------------------------------------
__global__ __launch_bounds__(256) void k_main(const float* __restrict__ f0,
                                              const float* __restrict__ cc,
                                              const float* __restrict__ vv,
                                              const float* __restrict__ rp,
                                              const double* __restrict__ P,
                                              float* __restrict__ out) {
    const int blk = blockIdx.x;           // 0 .. 2*FRAMES-1
    const int b = blk / FRAMES;
    const int t = blk - b * FRAMES;
    const int tid = threadIdx.x;
    const int wave = tid >> 6;
    const int k = tid & 63;

    // linear-interp coords for j = t*64 + k  (src is EXACT in f32)
    float src = (float)t + ((float)k - 31.5f) * (1.0f / 64.0f);
    src = fmaxf(src, 0.0f);
    int i0 = (int)src;
    int i1 = min(i0 + 1, FRAMES - 1);
    float w = src - (float)i0;
    float w1 = 1.0f - w;

    float acc = 0.0f;

    for (int pi = 0; pi < 2; ++pi) {
        const int p = wave * 2 + pi;
        const int bpi = b * POLY + p;
        const float* f0p = f0 + bpi * FRAMES;
        const float* vp  = vv + bpi * FRAMES;
        const float* cp  = cc + (size_t)bpi * HARM * FRAMES;
        const float* rpp = rp + bpi * HARM;

        const float f00 = f0p[i0];
        const float f01 = f0p[i1];
        const float v0  = vp[i0];
        const float v1  = vp[i1];
        const float vup04 = 0.04f * (w1 * v0 + w * v1);

        // per-sample phase increment (f64) and 64-lane inclusive scan
        double inc = ((double)w1 * (double)f00 + (double)w * (double)f01)
                     * (1.0 / (double)SR_I);
        double s = inc;
        #pragma unroll
        for (int off = 1; off < 64; off <<= 1) {
            double o = __shfl_up(s, off, 64);
            if (k >= off) s += o;
        }
        const double Phi = P[bpi * FRAMES + t] + s;   // inclusive cumsum at j

        // wave-wide harmonic cap: beyond hmax every lane is anti-alias masked
        float fmn = fminf(f00, f01);
        #pragma unroll
        for (int off = 32; off; off >>= 1)
            fmn = fminf(fmn, __shfl_xor(fmn, off, 64));
        const int hmax = min(HARM, (int)(NYQ / fmn));

        for (int n = 1; n <= hmax; ++n) {
            const float nf = (float)n;
            const float m0 = (f00 * nf < NYQ) ? 1.0f : 0.0f;
            const float m1 = (f01 * nf < NYQ) ? 1.0f : 0.0f;
            const float* cb = cp + (n - 1) * FRAMES;
            const float c0 = cb[i0] * m0;
            const float c1 = cb[i1] * m1;
            const float cup = w1 * c0 + w * c1;

            double ph = fma((double)nf, Phi, (double)rpp[n - 1]);
            double fr = ph - floor(ph);          // fractional revolutions
            float sv = __builtin_amdgcn_sinf((float)fr);  // sin(2*pi*fr)

            acc = fmaf(cup * vup04, sv, acc);
        }
    }

    __shared__ float part[4][64];
    part[wave][k] = acc;
    __syncthreads();
    if (tid < 64) {
        float sum = part[0][tid] + part[1][tid] + part[2][tid] + part[3][tid];
        out[(size_t)b * AUDIO + t * UP + tid] = sum;
    }
}

extern "C" void kernel_launch(void* const* d_in, const int* in_sizes, int n_in,
                              void* d_out, int out_size, void* d_ws, size_t ws_size,
                              hipStream_t stream) {
    const float* f0 = (const float*)d_in[0];   // (2,8,500)
    const float* c  = (const float*)d_in[1];   // (2,8,64,500)
    const float* v  = (const float*)d_in[2];   // (2,8,500)
    // d_in[3] = a (loudness) — unused by the output
    const float* rp = (const float*)d_in[4];   // (2,512,1)
    float* out = (float*)d_out;                // (2,32000)

    double* P = (double*)d_ws;                 // 16*500*8 = 64 KB

    k_prefix<<<2 * POLY, 64, 0, stream>>>(f0, P);
    k_main<<<2 * FRAMES, 256, 0, stream>>>(f0, c, v, rp, P, out);
}